// Round 1
// baseline (39.966 us; speedup 1.0000x reference)
//
#include <hip/hip_runtime.h>

#define TPB 256

__device__ __forceinline__ float rcp_(float x){ return __builtin_amdgcn_rcpf(x); }
__device__ __forceinline__ float rsq_(float x){ return __builtin_amdgcn_rsqf(x); }
__device__ __forceinline__ float sq_(float x){ return __builtin_amdgcn_sqrtf(x); }

// One exact Jacobi rotation on symmetric A (pair p,q; r = third index),
// accumulating V <- V*J. All operands passed as refs so everything stays in
// registers (no runtime-indexed arrays -> no scratch).
__device__ __forceinline__ void jrot(float &app, float &aqq, float &apq,
                                     float &arp, float &arq,
                                     float &v0p, float &v1p, float &v2p,
                                     float &v0q, float &v1q, float &v2q)
{
    if (apq * apq < 1e-30f) return;
    float theta = 0.5f * (aqq - app) * rcp_(apq);
    float t = copysignf(rcp_(fabsf(theta) + sq_(fmaf(theta, theta, 1.0f))), theta);
    float c = rsq_(fmaf(t, t, 1.0f));
    float s = t * c;
    app = fmaf(-t, apq, app);
    aqq = fmaf( t, apq, aqq);
    apq = 0.0f;
    float x, y;
    x = arp; y = arq; arp = fmaf(c, x, -s * y); arq = fmaf(s, x, c * y);
    x = v0p; y = v0q; v0p = fmaf(c, x, -s * y); v0q = fmaf(s, x, c * y);
    x = v1p; y = v1q; v1p = fmaf(c, x, -s * y); v1q = fmaf(s, x, c * y);
    x = v2p; y = v2q; v2p = fmaf(c, x, -s * y); v2q = fmaf(s, x, c * y);
}

// Givens QR step: zero element (j, k) against pivot (i, k).
// Rows i,j of B get [c s; -s c]; cols i,j of U get the transpose accumulate.
__device__ __forceinline__ void givens(float a1, float a2,
    float &bi0, float &bi1, float &bi2,
    float &bj0, float &bj1, float &bj2,
    float &ui0, float &ui1, float &ui2,
    float &uj0, float &uj1, float &uj2)
{
    float d = fmaf(a1, a1, a2 * a2);
    float c = 1.0f, s = 0.0f;
    if (d > 1e-30f) { float rr = rsq_(d); c = a1 * rr; s = a2 * rr; }
    float x, y;
    x = bi0; y = bj0; bi0 = fmaf(c, x, s * y); bj0 = fmaf(-s, x, c * y);
    x = bi1; y = bj1; bi1 = fmaf(c, x, s * y); bj1 = fmaf(-s, x, c * y);
    x = bi2; y = bj2; bi2 = fmaf(c, x, s * y); bj2 = fmaf(-s, x, c * y);
    x = ui0; y = uj0; ui0 = fmaf(c, x, s * y); uj0 = fmaf(-s, x, c * y);
    x = ui1; y = uj1; ui1 = fmaf(c, x, s * y); uj1 = fmaf(-s, x, c * y);
    x = ui2; y = uj2; ui2 = fmaf(c, x, s * y); uj2 = fmaf(-s, x, c * y);
}

__global__ __launch_bounds__(TPB) void svdo_kernel(const float* __restrict__ x,
                                                   float* __restrict__ out,
                                                   int nmat)
{
    __shared__ float lds[TPB * 9];
    const int tid = threadIdx.x;
    const int m0 = blockIdx.x * TPB;
    const int nm = min(TPB, nmat - m0);
    const int nflt = nm * 9;
    const float* src = x + (size_t)m0 * 9;

    // Stage in: contiguous float4 loads (block base is 9216B-aligned).
    if ((nflt & 3) == 0) {
        const float4* s4 = (const float4*)src;
        float4* d4 = (float4*)lds;
        for (int t = tid; t < (nflt >> 2); t += TPB) d4[t] = s4[t];
    } else {
        for (int t = tid; t < nflt; t += TPB) lds[t] = src[t];
    }
    __syncthreads();

    float r00=0,r01=0,r02=0,r10=0,r11=0,r12=0,r20=0,r21=0,r22=0;
    const bool active = tid < nm;
    if (active) {
        const float* mp = &lds[tid * 9];   // stride 9 is odd -> 2-way bank alias (free)
        float m00=mp[0], m01=mp[1], m02=mp[2];
        float m10=mp[3], m11=mp[4], m12=mp[5];
        float m20=mp[6], m21=mp[7], m22=mp[8];

        // A = M^T M (symmetric)
        float a00 = m00*m00 + m10*m10 + m20*m20;
        float a11 = m01*m01 + m11*m11 + m21*m21;
        float a22 = m02*m02 + m12*m12 + m22*m22;
        float a01 = m00*m01 + m10*m11 + m20*m21;
        float a02 = m00*m02 + m10*m12 + m20*m22;
        float a12 = m01*m02 + m11*m12 + m21*m22;

        // V = I
        float v00=1.f, v01=0.f, v02=0.f;
        float v10=0.f, v11=1.f, v12=0.f;
        float v20=0.f, v21=0.f, v22=1.f;

        // 4 cyclic Jacobi sweeps (12 rotations) -> A ~ diag(eigenvalues), V eigvecs
        #pragma unroll
        for (int sw = 0; sw < 4; ++sw) {
            jrot(a00, a11, a01, a02, a12, v00, v10, v20, v01, v11, v21); // (p,q)=(0,1), r=2
            jrot(a00, a22, a02, a01, a12, v00, v10, v20, v02, v12, v22); // (0,2), r=1
            jrot(a11, a22, a12, a01, a02, v01, v11, v21, v02, v12, v22); // (1,2), r=0
        }

        // Sort eigenvalues descending; swap V columns, negating one to keep det=+1
        float tswap;
        if (a00 < a11) {
            tswap = a00; a00 = a11; a11 = tswap;
            tswap = v00; v00 = v01; v01 = -tswap;
            tswap = v10; v10 = v11; v11 = -tswap;
            tswap = v20; v20 = v21; v21 = -tswap;
        }
        if (a00 < a22) {
            tswap = a00; a00 = a22; a22 = tswap;
            tswap = v00; v00 = v02; v02 = -tswap;
            tswap = v10; v10 = v12; v12 = -tswap;
            tswap = v20; v20 = v22; v22 = -tswap;
        }
        if (a11 < a22) {
            tswap = a11; a11 = a22; a22 = tswap;
            tswap = v01; v01 = v02; v02 = -tswap;
            tswap = v11; v11 = v12; v12 = -tswap;
            tswap = v21; v21 = v22; v22 = -tswap;
        }

        // B = M * V  (~= U * Sigma, Sigma's last entry carries sign of det(M))
        float b00 = m00*v00 + m01*v10 + m02*v20;
        float b01 = m00*v01 + m01*v11 + m02*v21;
        float b02 = m00*v02 + m01*v12 + m02*v22;
        float b10 = m10*v00 + m11*v10 + m12*v20;
        float b11 = m10*v01 + m11*v11 + m12*v21;
        float b12 = m10*v02 + m11*v12 + m12*v22;
        float b20 = m20*v00 + m21*v10 + m22*v20;
        float b21 = m20*v01 + m21*v11 + m22*v21;
        float b22 = m20*v02 + m21*v12 + m22*v22;

        // U = I
        float u00=1.f, u01=0.f, u02=0.f;
        float u10=0.f, u11=1.f, u12=0.f;
        float u20=0.f, u21=0.f, u22=1.f;

        // Givens QR of B: zero (1,0), (2,0), (2,1). U accumulates rotations.
        givens(b00, b10, b00, b01, b02, b10, b11, b12,
               u00, u10, u20, u01, u11, u21);
        givens(b00, b20, b00, b01, b02, b20, b21, b22,
               u00, u10, u20, u02, u12, u22);
        givens(b11, b21, b10, b11, b12, b20, b21, b22,
               u01, u11, u21, u02, u12, u22);

        // R = U * V^T
        r00 = u00*v00 + u01*v01 + u02*v02;
        r01 = u00*v10 + u01*v11 + u02*v12;
        r02 = u00*v20 + u01*v21 + u02*v22;
        r10 = u10*v00 + u11*v01 + u12*v02;
        r11 = u10*v10 + u11*v11 + u12*v12;
        r12 = u10*v20 + u11*v21 + u12*v22;
        r20 = u20*v00 + u21*v01 + u22*v02;
        r21 = u20*v10 + u21*v11 + u22*v12;
        r22 = u20*v20 + u21*v21 + u22*v22;
    }

    __syncthreads();
    if (active) {
        float* op = &lds[tid * 9];
        op[0]=r00; op[1]=r01; op[2]=r02;
        op[3]=r10; op[4]=r11; op[5]=r12;
        op[6]=r20; op[7]=r21; op[8]=r22;
    }
    __syncthreads();

    float* dst = out + (size_t)m0 * 9;
    if ((nflt & 3) == 0) {
        float4* d4 = (float4*)dst;
        const float4* s4 = (const float4*)lds;
        for (int t = tid; t < (nflt >> 2); t += TPB) d4[t] = s4[t];
    } else {
        for (int t = tid; t < nflt; t += TPB) dst[t] = lds[t];
    }
}

extern "C" void kernel_launch(void* const* d_in, const int* in_sizes, int n_in,
                              void* d_out, int out_size, void* d_ws, size_t ws_size,
                              hipStream_t stream)
{
    (void)n_in; (void)d_ws; (void)ws_size; (void)out_size;
    const float* x = (const float*)d_in[0];
    float* out = (float*)d_out;
    const int nmat = in_sizes[0] / 9;
    const int grid = (nmat + TPB - 1) / TPB;
    svdo_kernel<<<grid, TPB, 0, stream>>>(x, out, nmat);
}

// Round 2
// 39.771 us; speedup vs baseline: 1.0049x; 1.0049x over previous
//
#include <hip/hip_runtime.h>

#define TPB 256
#define MPB 512   // matrices per block: thread t owns matrices (t, t+256)

typedef float v2f __attribute__((ext_vector_type(2)));
typedef int   v2i __attribute__((ext_vector_type(2)));

static __device__ __forceinline__ v2f sqrt2(v2f a){
    v2f r; r.x = __builtin_amdgcn_sqrtf(a.x); r.y = __builtin_amdgcn_sqrtf(a.y); return r;
}
static __device__ __forceinline__ v2f rsq2(v2f a){
    v2f r; r.x = __builtin_amdgcn_rsqf(a.x); r.y = __builtin_amdgcn_rsqf(a.y); return r;
}
static __device__ __forceinline__ v2f csign2(v2f x, v2f y){
    v2f r; r.x = copysignf(x.x, y.x); r.y = copysignf(x.y, y.y); return r;
}
static __device__ __forceinline__ v2f fabs2(v2f x){
    v2f r; r.x = fabsf(x.x); r.y = fabsf(x.y); return r;
}
static __device__ __forceinline__ v2f sel2(v2i m, v2f a, v2f b){
    v2f r; r.x = m.x ? a.x : b.x; r.y = m.y ? a.y : b.y; return r;
}
// Jacobi/column rotation: p' = c*p - s*q ; q' = s*p + c*q
static __device__ __forceinline__ void rot2(v2f &p, v2f &q, v2f c, v2f s){
    v2f x = p, y = q; p = c*x - s*y; q = s*x + c*y;
}
// QR rotation: p' = c*p + s*q ; q' = c*q - s*p
static __device__ __forceinline__ void rotg2(v2f &p, v2f &q, v2f c, v2f s){
    v2f x = p, y = q; p = c*x + s*y; q = c*y - s*x;
}

// Exact cyclic-Jacobi rotation, 2 transcendentals (sqrt + rsqrt), branchless.
// Equivalent to Rutishauser: theta=(aqq-app)/(2 apq), t=sgn/( |th|+sqrt(th^2+1) ),
// c=1/sqrt(1+t^2), s=t*c; diag update via trace identity.
static __device__ __forceinline__ void jrot2(v2f &app, v2f &aqq, v2f &apq,
                                             v2f &arp, v2f &arq,
                                             v2f &v0p, v2f &v1p, v2f &v2p,
                                             v2f &v0q, v2f &v1q, v2f &v2q)
{
    v2f d   = aqq - app;
    v2f w   = apq + apq;
    v2f nrm = d*d + w*w;
    v2f rr  = sqrt2(nrm);
    v2f sr  = csign2(rr, d);          // sign(den) == sign(d)
    v2f den = d + sr;
    v2f inv = rsq2(den*den + w*w);
    v2f c   = fabs2(den) * inv;
    v2f s   = w * csign2(inv, den);
    v2i tiny = nrm < (v2f)1e-30f;
    c = sel2(tiny, (v2f)1.0f, c);
    s = sel2(tiny, (v2f)0.0f, s);
    v2f sum = app + aqq;
    v2f lo  = 0.5f*(sum - sr);        // lower-moving eigenvalue goes to app
    app = lo; aqq = sum - lo; apq = (v2f)0.0f;
    rot2(arp, arq, c, s);
    rot2(v0p, v0q, c, s);
    rot2(v1p, v1q, c, s);
    rot2(v2p, v2q, c, s);
}

static __device__ __forceinline__ void givens2(v2f a1, v2f a2,
    v2f &bi0, v2f &bi1, v2f &bi2, v2f &bj0, v2f &bj1, v2f &bj2,
    v2f &ui0, v2f &ui1, v2f &ui2, v2f &uj0, v2f &uj1, v2f &uj2)
{
    v2f d  = a1*a1 + a2*a2;
    v2f rr = rsq2(d);                  // inf when d==0; masked below
    v2i ok = d > (v2f)1e-30f;
    v2f c  = sel2(ok, a1*rr, (v2f)1.0f);
    v2f s  = sel2(ok, a2*rr, (v2f)0.0f);
    rotg2(bi0, bj0, c, s);
    rotg2(bi1, bj1, c, s);
    rotg2(bi2, bj2, c, s);
    rotg2(ui0, uj0, c, s);
    rotg2(ui1, uj1, c, s);
    rotg2(ui2, uj2, c, s);
}

__global__ __launch_bounds__(TPB) void svdo_kernel(const float* __restrict__ x,
                                                   float* __restrict__ out,
                                                   int nmat)
{
    __shared__ float lds[MPB * 9];
    const int tid = threadIdx.x;
    const int m0 = blockIdx.x * MPB;
    const int nm = min(MPB, nmat - m0);
    const int nflt = nm * 9;
    const float* src = x + (size_t)m0 * 9;

    if ((nflt & 3) == 0) {
        const float4* s4 = (const float4*)src; float4* d4 = (float4*)lds;
        for (int t = tid; t < (nflt >> 2); t += TPB) d4[t] = s4[t];
    } else {
        for (int t = tid; t < nflt; t += TPB) lds[t] = src[t];
    }
    __syncthreads();

    const bool act0 = tid < nm;
    const bool act1 = tid + TPB < nm;
    const int  i1   = act1 ? (tid + TPB) : 0;
    const float* p0 = &lds[tid * 9];   // stride-9 floats: 64 lanes spread all 32 banks (2/bank, free)
    const float* p1 = &lds[i1 * 9];

    v2f m00 = {p0[0], p1[0]}, m01 = {p0[1], p1[1]}, m02 = {p0[2], p1[2]};
    v2f m10 = {p0[3], p1[3]}, m11 = {p0[4], p1[4]}, m12 = {p0[5], p1[5]};
    v2f m20 = {p0[6], p1[6]}, m21 = {p0[7], p1[7]}, m22 = {p0[8], p1[8]};

    // A = M^T M
    v2f a00 = m00*m00 + m10*m10 + m20*m20;
    v2f a11 = m01*m01 + m11*m11 + m21*m21;
    v2f a22 = m02*m02 + m12*m12 + m22*m22;
    v2f a01 = m00*m01 + m10*m11 + m20*m21;
    v2f a02 = m00*m02 + m10*m12 + m20*m22;
    v2f a12 = m01*m02 + m11*m12 + m21*m22;

    v2f v00 = (v2f)1.0f, v01 = (v2f)0.0f, v02 = (v2f)0.0f;
    v2f v10 = (v2f)0.0f, v11 = (v2f)1.0f, v12 = (v2f)0.0f;
    v2f v20 = (v2f)0.0f, v21 = (v2f)0.0f, v22 = (v2f)1.0f;

    #pragma unroll
    for (int sw = 0; sw < 4; ++sw) {
        jrot2(a00, a11, a01, a02, a12, v00, v10, v20, v01, v11, v21); // (0,1) r=2
        jrot2(a00, a22, a02, a01, a12, v00, v10, v20, v02, v12, v22); // (0,2) r=1
        jrot2(a11, a22, a12, a01, a02, v01, v11, v21, v02, v12, v22); // (1,2) r=0
    }

    // Sort eigenvalues descending; column swaps negate one column to keep det(V)=+1
    v2f t;
    {
        v2i c01 = a00 < a11;
        t = a00; a00 = sel2(c01, a11, a00); a11 = sel2(c01, t, a11);
        t = v00; v00 = sel2(c01, v01, v00); v01 = sel2(c01, -t, v01);
        t = v10; v10 = sel2(c01, v11, v10); v11 = sel2(c01, -t, v11);
        t = v20; v20 = sel2(c01, v21, v20); v21 = sel2(c01, -t, v21);
    }
    {
        v2i c02 = a00 < a22;
        t = a00; a00 = sel2(c02, a22, a00); a22 = sel2(c02, t, a22);
        t = v00; v00 = sel2(c02, v02, v00); v02 = sel2(c02, -t, v02);
        t = v10; v10 = sel2(c02, v12, v10); v12 = sel2(c02, -t, v12);
        t = v20; v20 = sel2(c02, v22, v20); v22 = sel2(c02, -t, v22);
    }
    {
        v2i c12 = a11 < a22;
        t = a11; a11 = sel2(c12, a22, a11); a22 = sel2(c12, t, a22);
        t = v01; v01 = sel2(c12, v02, v01); v02 = sel2(c12, -t, v02);
        t = v11; v11 = sel2(c12, v12, v11); v12 = sel2(c12, -t, v12);
        t = v21; v21 = sel2(c12, v22, v21); v22 = sel2(c12, -t, v22);
    }

    // B = M * V  (~ U*Sigma; sign of det(M) rides on last column)
    v2f b00 = m00*v00 + m01*v10 + m02*v20;
    v2f b01 = m00*v01 + m01*v11 + m02*v21;
    v2f b02 = m00*v02 + m01*v12 + m02*v22;
    v2f b10 = m10*v00 + m11*v10 + m12*v20;
    v2f b11 = m10*v01 + m11*v11 + m12*v21;
    v2f b12 = m10*v02 + m11*v12 + m12*v22;
    v2f b20 = m20*v00 + m21*v10 + m22*v20;
    v2f b21 = m20*v01 + m21*v11 + m22*v21;
    v2f b22 = m20*v02 + m21*v12 + m22*v22;

    v2f u00 = (v2f)1.0f, u01 = (v2f)0.0f, u02 = (v2f)0.0f;
    v2f u10 = (v2f)0.0f, u11 = (v2f)1.0f, u12 = (v2f)0.0f;
    v2f u20 = (v2f)0.0f, u21 = (v2f)0.0f, u22 = (v2f)1.0f;

    // Givens QR of B: zero (1,0), (2,0), (2,1); U accumulates
    givens2(b00, b10, b00, b01, b02, b10, b11, b12,
            u00, u10, u20, u01, u11, u21);
    givens2(b00, b20, b00, b01, b02, b20, b21, b22,
            u00, u10, u20, u02, u12, u22);
    givens2(b11, b21, b10, b11, b12, b20, b21, b22,
            u01, u11, u21, u02, u12, u22);

    // R = U * V^T
    v2f r00 = u00*v00 + u01*v01 + u02*v02;
    v2f r01 = u00*v10 + u01*v11 + u02*v12;
    v2f r02 = u00*v20 + u01*v21 + u02*v22;
    v2f r10 = u10*v00 + u11*v01 + u12*v02;
    v2f r11 = u10*v10 + u11*v11 + u12*v12;
    v2f r12 = u10*v20 + u11*v21 + u12*v22;
    v2f r20 = u20*v00 + u21*v01 + u22*v02;
    v2f r21 = u20*v10 + u21*v11 + u22*v12;
    v2f r22 = u20*v20 + u21*v21 + u22*v22;

    __syncthreads();
    if (act0) {
        float* o = &lds[tid * 9];
        o[0]=r00.x; o[1]=r01.x; o[2]=r02.x;
        o[3]=r10.x; o[4]=r11.x; o[5]=r12.x;
        o[6]=r20.x; o[7]=r21.x; o[8]=r22.x;
    }
    if (act1) {
        float* o = &lds[(tid + TPB) * 9];
        o[0]=r00.y; o[1]=r01.y; o[2]=r02.y;
        o[3]=r10.y; o[4]=r11.y; o[5]=r12.y;
        o[6]=r20.y; o[7]=r21.y; o[8]=r22.y;
    }
    __syncthreads();

    float* dst = out + (size_t)m0 * 9;
    if ((nflt & 3) == 0) {
        float4* d4 = (float4*)dst; const float4* s4 = (const float4*)lds;
        for (int t2 = tid; t2 < (nflt >> 2); t2 += TPB) d4[t2] = s4[t2];
    } else {
        for (int t2 = tid; t2 < nflt; t2 += TPB) dst[t2] = lds[t2];
    }
}

extern "C" void kernel_launch(void* const* d_in, const int* in_sizes, int n_in,
                              void* d_out, int out_size, void* d_ws, size_t ws_size,
                              hipStream_t stream)
{
    (void)n_in; (void)d_ws; (void)ws_size; (void)out_size;
    const float* x = (const float*)d_in[0];
    float* out = (float*)d_out;
    const int nmat = in_sizes[0] / 9;
    const int grid = (nmat + MPB - 1) / MPB;
    svdo_kernel<<<grid, TPB, 0, stream>>>(x, out, nmat);
}